// Round 5
// baseline (346.151 us; speedup 1.0000x reference)
//
#include <hip/hip_runtime.h>

#define BB 8
#define SS 4096
#define HIDD 1024
#define HH 16
#define DHH 64

// K1: weff[o][i], o<16: sum_d aw[o,d]*Wq[o*64+d, i]; o>=16: same with Wk.
// wq_f and wk_f are adjacent in ws => weff = wq_f is [32][1024].
// grid (4, 16, 2), block 256
__global__ __launch_bounds__(256) void k_prep(const float* __restrict__ Wq,
                                              const float* __restrict__ Wk,
                                              const float* __restrict__ aw,
                                              float* __restrict__ wq_f,
                                              float* __restrict__ wk_f) {
    int i = blockIdx.x * 256 + threadIdx.x;
    int h = blockIdx.y;
    const float* W = blockIdx.z ? Wk : Wq;
    float* outp = blockIdx.z ? wk_f : wq_f;
    float acc = 0.f;
#pragma unroll
    for (int d = 0; d < DHH; ++d) {
        acc += aw[h * DHH + d] * W[(size_t)(h * DHH + d) * HIDD + i];
    }
    outp[h * HIDD + i] = acc;
}

// K2 v8: scores[32768][32] = hid x weff^T.
// Round-4 counters: VALU 41us (3x FMA floor: swizzle-XOR addr math) + DS pipe
// ~60us (4.2M broadcast weight reads, 1 useful f4 per instr).
// Fixes: (a) R=2 rows/lane -> 128-row blocks, grid 256: weight reads halve;
// (b) stride-17-f4 LDS layout (row stride 272B: lane-to-bank stride 4 ->
// 2 lanes/bank-pair = free) set up via the GLOBAL source address at staging
// (slot f -> row f/17, col f%17; col-16 slots get dummy data) so LDS dests
// stay linear for global_load_lds and EVERY inner ds_read_b128 is
// base + compile-time offset: -> zero per-kc address VALU.
// Block 512 = 8 waves x 4 outs; weights staged to LDS (broadcast reads,
// imm-offset); all-DS inner loop (counted lgkmcnt, no SMEM poison).
#define KC 64
#define NCH (HIDD / KC)
__global__ __launch_bounds__(512) void k_scores(const float* __restrict__ hid,
                                                const float* __restrict__ mask,
                                                const float* __restrict__ weff,
                                                float* __restrict__ qsb,
                                                float* __restrict__ ksb) {
    __shared__ float shh[2][128 * 17 * 4];   // 2 x 34816 B, row stride 17 f4
    __shared__ float shw[2][32 * 16 * 4];    // 2 x 8192 B, 32 outs x 16 f4

    const int t    = threadIdx.x;         // 0..511
    const int lane = t & 63;
    const int wave = t >> 6;              // 0..7
    const int obase = __builtin_amdgcn_readfirstlane(wave * 4);  // 0..28

    const int row0 = blockIdx.x * 128 + lane;       // global rows (b*4096+s)
    const int row1 = row0 + 64;
    const size_t gbase = (size_t)blockIdx.x * 128 * HIDD;

    // staging descriptors: 2176 hid slots (128 rows x 17 f4) = 4/thread + 1
    // extra for t<128. slot f: r=f/17, c=f%17 (c==16 -> dummy col 0).
    int srow[5], scol[5];
#pragma unroll
    for (int j = 0; j < 5; ++j) {
        int f = (j < 4) ? (j * 512 + t) : (2048 + t);
        int r = f / 17;
        int c = f - r * 17;
        srow[j] = r;
        scol[j] = (c == 16) ? 0 : c;
    }
    const bool extra = (t < 128);

    auto stage = [&](int chunk, int buf) {
#pragma unroll
        for (int j = 0; j < 4; ++j) {
            const float* gp = hid + gbase + (size_t)srow[j] * HIDD
                              + chunk * KC + scol[j] * 4;
            float* lp = &shh[buf][(j * 512 + t) * 4];
            __builtin_amdgcn_global_load_lds(
                (const __attribute__((address_space(1))) void*)gp,
                (__attribute__((address_space(3))) void*)lp, 16, 0, 0);
        }
        if (extra) {
            const float* gp = hid + gbase + (size_t)srow[4] * HIDD
                              + chunk * KC + scol[4] * 4;
            float* lp = &shh[buf][(2048 + t) * 4];
            __builtin_amdgcn_global_load_lds(
                (const __attribute__((address_space(1))) void*)gp,
                (__attribute__((address_space(3))) void*)lp, 16, 0, 0);
        }
        {   // weights: 512 slots, 1/thread, linear (out t>>4, f4-col t&15)
            const float* gp = weff + (size_t)(t >> 4) * HIDD
                              + chunk * KC + (t & 15) * 4;
            float* lp = &shw[buf][t * 4];
            __builtin_amdgcn_global_load_lds(
                (const __attribute__((address_space(1))) void*)gp,
                (__attribute__((address_space(3))) void*)lp, 16, 0, 0);
        }
    };

    float acc0[4] = {0.f, 0.f, 0.f, 0.f};
    float acc1[4] = {0.f, 0.f, 0.f, 0.f};

    stage(0, 0);

    for (int chunk = 0; chunk < NCH; ++chunk) {
        const int buf = chunk & 1;
        asm volatile("s_waitcnt vmcnt(0)" ::: "memory");  // own stage done
        __syncthreads();                                  // all stages done
        if (chunk + 1 < NCH) stage(chunk + 1, buf ^ 1);   // prefetch

        const float* h0 = &shh[buf][lane * 68];           // 17 f4 = 68 floats
        const float* h1 = &shh[buf][(lane + 64) * 68];
        const float* wb = &shw[buf][obase * 64];          // 16 f4 = 64 floats
#pragma unroll
        for (int kc = 0; kc < 16; ++kc) {
            float4 a0 = *reinterpret_cast<const float4*>(h0 + kc * 4);
            float4 a1 = *reinterpret_cast<const float4*>(h1 + kc * 4);
#pragma unroll
            for (int o = 0; o < 4; ++o) {
                float4 wv = *reinterpret_cast<const float4*>(wb + o * 64 + kc * 4);
                acc0[o] += a0.x * wv.x + a0.y * wv.y + a0.z * wv.z + a0.w * wv.w;
                acc1[o] += a1.x * wv.x + a1.y * wv.y + a1.z * wv.z + a1.w * wv.w;
            }
        }
    }

    float m0 = mask[row0];
    float m1 = mask[row1];
#pragma unroll
    for (int o = 0; o < 4; ++o) { acc0[o] *= m0; acc1[o] *= m1; }

    float4 v0 = make_float4(acc0[0], acc0[1], acc0[2], acc0[3]);
    float4 v1 = make_float4(acc1[0], acc1[1], acc1[2], acc1[3]);
    if (obase < 16) {
        *reinterpret_cast<float4*>(qsb + (size_t)row0 * 16 + obase) = v0;
        *reinterpret_cast<float4*>(qsb + (size_t)row1 * 16 + obase) = v1;
    } else {
        *reinterpret_cast<float4*>(ksb + (size_t)row0 * 20 + (obase - 16)) = v0;
        *reinterpret_cast<float4*>(ksb + (size_t)row1 * 20 + (obase - 16)) = v1;
        if (obase == 16) {
            ksb[(size_t)row0 * 20 + 16] = m0;
            ksb[(size_t)row1 * 20 + 16] = m1;
        }
    }
}

// K3 v3: NO atomics. Thread owns 4 cols (float4 loads, 68 accumulators),
// s-chunk 64 rows -> grid (64, 8) = 512 blocks = 2/CU.
// part[schunk][b][17][1024]: ksh partial (16 ch) + hsum partial (mask ch).
__global__ __launch_bounds__(256) void k_ksh(const float* __restrict__ hid,
                                             const float* __restrict__ ksb,
                                             float* __restrict__ part) {
    int b  = blockIdx.y;
    int i  = threadIdx.x * 4;
    int s0 = blockIdx.x * 64;

    float4 acc[17];
#pragma unroll
    for (int c = 0; c < 17; ++c) acc[c] = make_float4(0.f, 0.f, 0.f, 0.f);

    const float* hb = hid + (size_t)(b * SS + s0) * HIDD + i;
    const float* sb = ksb + (size_t)(b * SS + s0) * 20;

#pragma unroll 4
    for (int s = 0; s < 64; ++s) {
        float4 hv = *reinterpret_cast<const float4*>(hb + (size_t)s * HIDD);
        const float* sc = sb + s * 20;
#pragma unroll
        for (int c = 0; c < 17; ++c) {
            float scv = sc[c];
            acc[c].x += scv * hv.x;
            acc[c].y += scv * hv.y;
            acc[c].z += scv * hv.z;
            acc[c].w += scv * hv.w;
        }
    }

    float* pb = part + (((size_t)blockIdx.x * 8 + b) * 17) * 1024 + i;
#pragma unroll
    for (int c = 0; c < 17; ++c) {
        *reinterpret_cast<float4*>(pb + c * 1024) = acc[c];
    }
}

// K3b: reduce 64 schunk partials -> ksh[b][16][1024], hsum[b][1024].
// grid 544, block 256 (544*256 = 8*17*1024 outputs exactly)
__global__ __launch_bounds__(256) void k_red(const float* __restrict__ part,
                                             float* __restrict__ ksh,
                                             float* __restrict__ hsum) {
    int gid = blockIdx.x * 256 + threadIdx.x;
    int b = gid / 17408;               // 17*1024
    int r = gid - b * 17408;
    int c = r >> 10;
    int i = r & 1023;

    float s = 0.f;
#pragma unroll 8
    for (int k = 0; k < 64; ++k)
        s += part[(((size_t)k * 8 + b) * 17 + c) * 1024 + i];

    if (c < 16) ksh[((size_t)b * 16 + c) * 1024 + i] = s;
    else        hsum[b * 1024 + i] = s;
}

// K4 v2: mvn[b,j] = (Wv[j,:]·hsum[b,:])/len;  kvn[b,j] = (Wv[j,:]·ksh[b,j/64,:])/len
// grid (8, 32), block 256: 32 j per block, 8 lanes split each 1024-dot,
// __shfl_xor reduce over the 8-lane group.
__global__ __launch_bounds__(256) void k_fin(const float* __restrict__ Wv,
                                             const float* __restrict__ mask,
                                             const float* __restrict__ hsum,
                                             const float* __restrict__ ksh,
                                             float* __restrict__ mvn,
                                             float* __restrict__ kvn) {
    int b  = blockIdx.x;
    int j  = blockIdx.y * 32 + (threadIdx.x >> 3);
    int sl = threadIdx.x & 7;

    __shared__ float red[256];
    float lsum = 0.f;
    for (int s = threadIdx.x; s < SS; s += 256) lsum += mask[b * SS + s];
    red[threadIdx.x] = lsum;
    __syncthreads();
    for (int off = 128; off; off >>= 1) {
        if (threadIdx.x < off) red[threadIdx.x] += red[threadIdx.x + off];
        __syncthreads();
    }
    float invlen = 1.0f / red[0];

    int h = j >> 6;
    const float4* w4 = reinterpret_cast<const float4*>(Wv + (size_t)j * HIDD + sl * 128);
    const float4* hv = reinterpret_cast<const float4*>(hsum + b * HIDD + sl * 128);
    const float4* kv = reinterpret_cast<const float4*>(ksh + ((size_t)b * 16 + h) * HIDD + sl * 128);

    float mv = 0.f, kvv = 0.f;
#pragma unroll
    for (int c = 0; c < 32; ++c) {
        float4 w = w4[c], a = hv[c], k2 = kv[c];
        mv  += w.x * a.x  + w.y * a.y  + w.z * a.z  + w.w * a.w;
        kvv += w.x * k2.x + w.y * k2.y + w.z * k2.z + w.w * k2.w;
    }
#pragma unroll
    for (int off = 1; off < 8; off <<= 1) {
        mv  += __shfl_xor(mv, off);
        kvv += __shfl_xor(kvv, off);
    }
    if (sl == 0) {
        mvn[b * HIDD + j] = mv * invlen;
        kvn[b * HIDD + j] = kvv * invlen;
    }
}

// K5: out[b,s,j] = q_score[b,s,j/64]*mvn[b,j] + kvn[b,j], float4 stores.
// grid 16384, block 256, 8 elems/thread
__global__ __launch_bounds__(256) void k_out(const float* __restrict__ qsb,
                                             const float* __restrict__ mvn,
                                             const float* __restrict__ kvn,
                                             float* __restrict__ outp) {
    size_t e0 = ((size_t)blockIdx.x * 256 + threadIdx.x) * 8;
    int b   = (int)(e0 >> 22);                 // 4096*1024 = 2^22
    int rem = (int)(e0 & ((1u << 22) - 1));
    int s   = rem >> 10;
    int j   = rem & 1023;

    float q = qsb[(size_t)(b * SS + s) * 16 + (j >> 6)];
    const float4* mv4 = reinterpret_cast<const float4*>(mvn + b * HIDD + j);
    const float4* kv4 = reinterpret_cast<const float4*>(kvn + b * HIDD + j);
    float4 m0 = mv4[0], m1 = mv4[1];
    float4 k0 = kv4[0], k1 = kv4[1];

    float4 o0, o1;
    o0.x = q * m0.x + k0.x;  o0.y = q * m0.y + k0.y;
    o0.z = q * m0.z + k0.z;  o0.w = q * m0.w + k0.w;
    o1.x = q * m1.x + k1.x;  o1.y = q * m1.y + k1.y;
    o1.z = q * m1.z + k1.z;  o1.w = q * m1.w + k1.w;

    float4* op = reinterpret_cast<float4*>(outp + e0);
    op[0] = o0;
    op[1] = o1;
}

extern "C" void kernel_launch(void* const* d_in, const int* in_sizes, int n_in,
                              void* d_out, int out_size, void* d_ws, size_t ws_size,
                              hipStream_t stream) {
    const float* hid  = (const float*)d_in[0];   // (B,S,HID)
    const float* mask = (const float*)d_in[1];   // (B,1,1,S)
    const float* Wq   = (const float*)d_in[2];   // (HID,HID)
    const float* Wk   = (const float*)d_in[3];
    const float* Wv   = (const float*)d_in[4];
    const float* aw   = (const float*)d_in[5];   // (H,1,DH)
    float* outp = (float*)d_out;

    float* ws   = (float*)d_ws;
    float* wq_f = ws;                       // 16384   } weff[32][1024]
    float* wk_f = wq_f + 16384;             // 16384   } (adjacent)
    float* qsb  = wk_f + 16384;             // 8*4096*16 = 524288
    float* ksb  = qsb + 524288;             // 8*4096*20 = 655360
    float* ksh  = ksb + 655360;             // 8*16*1024 = 131072
    float* hsum = ksh + 131072;             // 8*1024   = 8192
    float* mvn  = hsum + 8192;              // 8192
    float* kvn  = mvn + 8192;               // 8192
    float* part = kvn + 8192;               // 64*8*17*1024 = 8912896 (~35.7 MB)

    k_prep  <<<dim3(4, 16, 2), 256, 0, stream>>>(Wq, Wk, aw, wq_f, wk_f);
    k_scores<<<dim3(256),      512, 0, stream>>>(hid, mask, wq_f, qsb, ksb);
    k_ksh   <<<dim3(64, 8),    256, 0, stream>>>(hid, ksb, part);
    k_red   <<<dim3(544),      256, 0, stream>>>(part, ksh, hsum);
    k_fin   <<<dim3(8, 32),    256, 0, stream>>>(Wv, mask, hsum, ksh, mvn, kvn);
    k_out   <<<dim3(16384),    256, 0, stream>>>(qsb, mvn, kvn, outp);
}